// Round 10
// baseline (361.967 us; speedup 1.0000x reference)
//
#include <hip/hip_runtime.h>
#include <hip/hip_bf16.h>
#include <hip/hip_fp16.h>

#define B_N 16
#define L_N 9216
#define LT64 144    // L_N / 64

typedef __attribute__((ext_vector_type(8))) short short8;
typedef __attribute__((ext_vector_type(4))) float floatx4;

__device__ __forceinline__ float bfu(unsigned short u) {
  return __uint_as_float(((unsigned int)u) << 16);
}
__device__ __forceinline__ unsigned short fbf(float f) {
  __hip_bfloat16 h = __float2bfloat16(f);
  return *(unsigned short*)&h;
}
__device__ __forceinline__ unsigned short fh(float f) {
  __half h = __float2half(f);
  return *(unsigned short*)&h;
}
__device__ __forceinline__ float hfu(unsigned short u) {
  __half h = *(__half*)&u;
  return __half2float(h);
}

// ---------------------------------------------------------------------------
// K0: weights fp32 -> bf16
// ---------------------------------------------------------------------------
__global__ __launch_bounds__(256) void k_prep(const float* __restrict__ w1,
                                              const float* __restrict__ w2,
                                              __hip_bfloat16* __restrict__ w1bt,
                                              __hip_bfloat16* __restrict__ w2bt) {
  int i = blockIdx.x * 256 + threadIdx.x;
  if (i < 256 * 128) w1bt[i] = __float2bfloat16(w1[i]);
  if (i < 128 * 128) w2bt[i] = __float2bfloat16(w2[i]);
}

// ---------------------------------------------------------------------------
// K1: in_proj MFMA (M=256e x N=80l x K=128c), 8 waves x 2mi x 5ni.
// One-phase epilogue (acc dies there -> VGPR ~40, no spill; R6/R7 lesson).
// LDS shrunk to 37.9KB for 4 blocks/CU: cvs stored fp16 [128][72] (err 5e-4,
// absorbed by bf16 output rounding), x_proj partials accumulated via LDS
// atomicAdd into separate red[12][64] (replaces 24KB red[8][..] + reduce).
// Fused dt_proj + softplus tail -> dth fp16; xdbl4 = B,C rows only.
// ---------------------------------------------------------------------------
__global__ __launch_bounds__(512, 4) void k_inproj_conv(
    const float* __restrict__ x, const __hip_bfloat16* __restrict__ w1bt,
    const float* __restrict__ cw, const float* __restrict__ cb,
    const float* __restrict__ xpw, const float* __restrict__ dtw,
    const float* __restrict__ dtb,
    __hip_bfloat16* __restrict__ xinb, __hip_bfloat16* __restrict__ zb,
    float* __restrict__ xdbl4, unsigned short* __restrict__ dth) {
  __shared__ __align__(16) char smem1[16384];   // xs swizzled [64 l][128 c] bf16
  __shared__ __align__(16) char smem2[18432];   // xe bf16[16][128] -> cvs fp16[128][72]
  __shared__ __align__(16) float red[12][64];   // x_proj sums (atomicAdd)
  unsigned short* xs = (unsigned short*)smem1;
  unsigned short* xe = (unsigned short*)smem2;  // swizzled [16 l][128 c]
  unsigned short (*cvs)[72] = (unsigned short(*)[72])smem2;

  int blk = blockIdx.x, b = blk / LT64, lt = blk % LT64, l0 = lt * 64;
  int t = threadIdx.x;
  int lane = t & 63, wv = t >> 6;
  int col = lane & 15, quad = lane >> 4;

  // zero the atomic accumulator (ordered before use by B1/B1b/B2 barriers)
  {
    float* rf = (float*)red;
    rf[t] = 0.f;
    if (t < 256) rf[512 + t] = 0.f;
  }

  // ---- stage x fp32 -> bf16 scattered into swizzled xe (16 l) + xs (64 l) ----
  const float* xb = x + (size_t)b * 128 * L_N + l0 - 16;
#pragma unroll
  for (int i = 0; i < 5; ++i) {
    int idx = t + i * 512;                     // 0..2559: 128 c x 20 q
    int c = idx & 127, q = idx >> 7;
    float4 v = {0.f, 0.f, 0.f, 0.f};
    if (!(lt == 0 && q < 4)) v = *(const float4*)(xb + (size_t)c * L_N + q * 4);
    int ch = c >> 3, ce = c & 7;
    if (q < 4) {
#pragma unroll
      for (int j = 0; j < 4; ++j) {
        int l = q * 4 + j;                     // 0..15
        xe[l * 128 + (((ch ^ (l & 7)) << 3) | ce)] = fbf(((const float*)&v)[j]);
      }
    } else {
#pragma unroll
      for (int j = 0; j < 4; ++j) {
        int l = q * 4 - 16 + j;                // 0..63
        xs[l * 128 + (((ch ^ (l & 7)) << 3) | ce)] = fbf(((const float*)&v)[j]);
      }
    }
  }

  int e0 = wv * 32;
  const __hip_bfloat16* wbp = w1bt + (size_t)(e0 + col) * 128 + quad * 8;
  floatx4 vzero = {0.f, 0.f, 0.f, 0.f};
  floatx4 acc[2][5];
#pragma unroll
  for (int mi = 0; mi < 2; ++mi)
#pragma unroll
    for (int ni = 0; ni < 5; ++ni) acc[mi][ni] = vzero;
  short8 a0 = *(const short8*)(wbp);
  short8 a1 = *(const short8*)(wbp + 16 * 128);
  __syncthreads();                             // B1: xe + xs ready

#pragma unroll
  for (int ks = 0; ks < 4; ++ks) {
    short8 n0, n1;
    if (ks < 3) {
      n0 = *(const short8*)(wbp + (ks + 1) * 32);
      n1 = *(const short8*)(wbp + 16 * 128 + (ks + 1) * 32);
    }
    short8 bfr[5];
    bfr[0] = *(const short8*)&xe[col * 128 + (((ks * 4 + quad) ^ (col & 7)) << 3)];
#pragma unroll
    for (int ni = 1; ni < 5; ++ni) {
      int row = (ni - 1) * 16 + col;
      bfr[ni] = *(const short8*)&xs[row * 128 + (((ks * 4 + quad) ^ (row & 7)) << 3)];
    }
#pragma unroll
    for (int ni = 0; ni < 5; ++ni) {
      acc[0][ni] = __builtin_amdgcn_mfma_f32_16x16x32_bf16(a0, bfr[ni], acc[0][ni], 0, 0, 0);
      acc[1][ni] = __builtin_amdgcn_mfma_f32_16x16x32_bf16(a1, bfr[ni], acc[1][ni], 0, 0, 0);
    }
    a0 = n0; a1 = n1;
  }
  __syncthreads();                             // B1b: LDS reads done; xe dead

  // epilogue (ONE phase): waves 0-3 -> cvs fp16 d=0..127; waves 4-7 -> z global
  if (wv >= 4) {
    __hip_bfloat16* zbase = zb + ((size_t)b * 128 + (e0 - 128)) * L_N + l0;
#pragma unroll
    for (int mi = 0; mi < 2; ++mi)
#pragma unroll
      for (int r = 0; r < 4; ++r) {
        int dr = mi * 16 + quad * 4 + r;       // within this wave's 32-row strip
#pragma unroll
        for (int ni = 1; ni < 5; ++ni)
          zbase[(size_t)dr * L_N + (ni - 1) * 16 + col] = __float2bfloat16(acc[mi][ni][r]);
      }
  } else {
#pragma unroll
    for (int mi = 0; mi < 2; ++mi)
#pragma unroll
      for (int r = 0; r < 4; ++r) {
        int d = e0 + mi * 16 + quad * 4 + r;   // 0..127
        if (col >= 13) cvs[d][col - 13] = fh(acc[mi][0][r]);
#pragma unroll
        for (int ni = 1; ni < 5; ++ni) cvs[d][3 + (ni - 1) * 16 + col] = fh(acc[mi][ni][r]);
      }
  }
  __syncthreads();                             // B2: cvs ready

  // conv + SiLU + x_proj partials; wave wv owns d in [wv*16, wv*16+16)
  float part[12];
#pragma unroll
  for (int m = 0; m < 12; ++m) part[m] = 0.f;
  for (int dd = 0; dd < 16; ++dd) {
    int d = wv * 16 + dd;
    float v = cb[d] + cw[d * 4 + 0] * hfu(cvs[d][lane]) + cw[d * 4 + 1] * hfu(cvs[d][lane + 1])
                    + cw[d * 4 + 2] * hfu(cvs[d][lane + 2]) + cw[d * 4 + 3] * hfu(cvs[d][lane + 3]);
    v = v / (1.f + __expf(-v));                // SiLU
    xinb[((size_t)b * 128 + d) * L_N + l0 + lane] = __float2bfloat16(v);
#pragma unroll
    for (int m = 0; m < 12; ++m) part[m] += xpw[m * 128 + d] * v;
  }
#pragma unroll
  for (int m = 0; m < 12; ++m) atomicAdd(&red[m][lane], part[m]);
  __syncthreads();                             // B3: red = x_dbl[12][64]

  if (t < 256) {                               // B,C rows -> xdbl4 global
    int m = 8 + (t >> 6), l = t & 63;
    xdbl4[((size_t)b * 4 + (m - 8)) * L_N + l0 + l] = red[m][l];
  }
  // fused dt_proj + softplus -> dth fp16; wave wv owns d in [wv*16,wv*16+16)
  float xd[8];
#pragma unroll
  for (int r = 0; r < 8; ++r) xd[r] = red[r][lane];
  for (int dd = 0; dd < 16; ++dd) {
    int d = wv * 16 + dd;
    float p = dtb[d];
#pragma unroll
    for (int r = 0; r < 8; ++r) p += dtw[d * 8 + r] * xd[r];
    float dt = (p > 15.f) ? p : __logf(1.f + __expf(p));
    dth[((size_t)b * 128 + d) * L_N + l0 + lane] = fh(dt);
  }
}

// ---------------------------------------------------------------------------
// K3: scan (D_STATE=2) + y + z-gate.  dt pre-computed (post-softplus, fp16).
// Single barrier per tile: agg + carry double-buffered on tile parity.
// Block per (b,d); 9 tiles of 1024 l; serial 4/lane + wave KS + block carry.
// ---------------------------------------------------------------------------
__global__ __launch_bounds__(256) void k_scan(
    const float* __restrict__ xdbl4, const unsigned short* __restrict__ dth,
    const float* __restrict__ alog, const float* __restrict__ dpar,
    const __hip_bfloat16* __restrict__ xinb, const __hip_bfloat16* __restrict__ zb,
    __hip_bfloat16* __restrict__ yb) {
  __shared__ float agg[2][4][4];
  __shared__ float carry[2][2];
  int blk = blockIdx.x, b = blk >> 7, d = blk & 127;
  int t = threadIdx.x, lane = t & 63, wv = t >> 6;
  float A0 = -__expf(alog[2 * d]), A1 = -__expf(alog[2 * d + 1]);
  float Dv = dpar[d];
  if (t == 0) { carry[0][0] = 0.f; carry[0][1] = 0.f; }
  __syncthreads();
  const float* xdT = xdbl4 + (size_t)b * 4 * L_N;
  const unsigned short* dtp_ = dth + ((size_t)b * 128 + d) * L_N;
  const unsigned short* xi = (const unsigned short*)xinb + ((size_t)b * 128 + d) * L_N;
  const unsigned short* zr = (const unsigned short*)zb + ((size_t)b * 128 + d) * L_N;
  unsigned short* yo = (unsigned short*)yb + ((size_t)b * 128 + d) * L_N;
  for (int it = 0; it < 9; ++it) {
    int p = it & 1;
    int lb = it * 1024 + t * 4;
    float4 q[4];
#pragma unroll
    for (int m = 0; m < 4; ++m) q[m] = *(const float4*)(xdT + (size_t)m * L_N + lb);
    ushort4 du = *(const ushort4*)(dtp_ + lb);
    ushort4 xu = *(const ushort4*)(xi + lb);
    ushort4 zu = *(const ushort4*)(zr + lb);
    float dtv[4] = {hfu(du.x), hfu(du.y), hfu(du.z), hfu(du.w)};
    float xv[4] = {bfu(xu.x), bfu(xu.y), bfu(xu.z), bfu(xu.w)};
    float zv[4] = {bfu(zu.x), bfu(zu.y), bfu(zu.z), bfu(zu.w)};
    float A0p[4], X0p[4], A1p[4], X1p[4];
#pragma unroll
    for (int j = 0; j < 4; ++j) {
      float dt = dtv[j];
      float a0 = __expf(dt * A0), a1 = __expf(dt * A1);
      float dtx = dt * xv[j];
      float x0 = dtx * ((const float*)&q[0])[j];   // B state 0
      float x1 = dtx * ((const float*)&q[1])[j];   // B state 1
      if (j == 0) { A0p[0] = a0; X0p[0] = x0; A1p[0] = a1; X1p[0] = x1; }
      else {
        A0p[j] = a0 * A0p[j - 1]; X0p[j] = a0 * X0p[j - 1] + x0;
        A1p[j] = a1 * A1p[j - 1]; X1p[j] = a1 * X1p[j - 1] + x1;
      }
    }
    float wA0 = A0p[3], wX0 = X0p[3], wA1 = A1p[3], wX1 = X1p[3];
#pragma unroll
    for (int off = 1; off < 64; off <<= 1) {
      float pA0 = __shfl_up(wA0, off, 64), pX0 = __shfl_up(wX0, off, 64);
      float pA1 = __shfl_up(wA1, off, 64), pX1 = __shfl_up(wX1, off, 64);
      if (lane >= off) {
        wX0 += wA0 * pX0; wA0 *= pA0;
        wX1 += wA1 * pX1; wA1 *= pA1;
      }
    }
    if (lane == 63) { agg[p][wv][0] = wA0; agg[p][wv][1] = wX0; agg[p][wv][2] = wA1; agg[p][wv][3] = wX1; }
    float eA0 = __shfl_up(wA0, 1, 64), eX0 = __shfl_up(wX0, 1, 64);
    float eA1 = __shfl_up(wA1, 1, 64), eX1 = __shfl_up(wX1, 1, 64);
    if (lane == 0) { eA0 = 1.f; eX0 = 0.f; eA1 = 1.f; eX1 = 0.f; }
    __syncthreads();                           // agg[p] + carry[p] ready
    float h0 = carry[p][0], h1 = carry[p][1];
    for (int jw = 0; jw < wv; ++jw) {          // wave-uniform
      h0 = agg[p][jw][0] * h0 + agg[p][jw][1];
      h1 = agg[p][jw][2] * h1 + agg[p][jw][3];
    }
    h0 = eA0 * h0 + eX0;                       // lane input state
    h1 = eA1 * h1 + eX1;
    if (t == 255) {                            // writes OTHER buffer: no race
      carry[p ^ 1][0] = A0p[3] * h0 + X0p[3];
      carry[p ^ 1][1] = A1p[3] * h1 + X1p[3];
    }
    ushort4 yu;
    unsigned short* yp = (unsigned short*)&yu;
#pragma unroll
    for (int j = 0; j < 4; ++j) {
      float hh0 = A0p[j] * h0 + X0p[j];
      float hh1 = A1p[j] * h1 + X1p[j];
      float y = hh0 * ((const float*)&q[2])[j] + hh1 * ((const float*)&q[3])[j] + Dv * xv[j];
      y *= zv[j] / (1.f + __expf(-zv[j]));
      yp[j] = fbf(y);
    }
    *(ushort4*)(yo + lb) = yu;
  }
}

// ---------------------------------------------------------------------------
// K4: out_proj MFMA (M=128o x N=64l x K=128d) + LayerNorm + NCHW write.
// ---------------------------------------------------------------------------
__global__ __launch_bounds__(256) void k_outln(
    const __hip_bfloat16* __restrict__ yb, const __hip_bfloat16* __restrict__ w2bt,
    const float* __restrict__ gam, const float* __restrict__ bet,
    float* __restrict__ out) {
  __shared__ unsigned short st[128][68];
  __shared__ __hip_bfloat16 yts[64 * 128];
  __shared__ float red_s[4][64], red_q[4][64];
  __shared__ float gs[128], bs[128];
  int blk = blockIdx.x, b = blk / LT64, lt = blk % LT64, l0 = lt * 64;
  int t = threadIdx.x;
  if (t < 128) { gs[t] = gam[t]; bs[t] = bet[t]; }
  const unsigned short* ybb = (const unsigned short*)yb + (size_t)b * 128 * L_N + l0;
#pragma unroll
  for (int i = 0; i < 8; ++i) {
    int idx = t + i * 256;              // 2048 ushort4 loads (128d x 16 l-quads)
    int dd = idx >> 4, l4 = (idx & 15) * 4;
    ushort4 v = *(const ushort4*)(ybb + (size_t)dd * L_N + l4);
    *(ushort4*)&st[dd][l4] = v;
  }
  __syncthreads();
#pragma unroll
  for (int p = 0; p < 4; ++p) {
    int gi = t + p * 256;               // 1024 chunk-packs (64 l x 16 ch)
    int l = gi & 63, ch = gi >> 6;
    short8 c;
#pragma unroll
    for (int j = 0; j < 8; ++j) c[j] = (short)st[ch * 8 + j][l];
    *(short8*)&yts[l * 128 + ((ch ^ (l & 7)) * 8)] = c;
  }
  int lane = t & 63, wv = t >> 6;
  int col = lane & 15, quad = lane >> 4;
  int o0 = wv * 32;
  short8 afr[2][4];
#pragma unroll
  for (int mi = 0; mi < 2; ++mi)
#pragma unroll
    for (int ks = 0; ks < 4; ++ks)
      afr[mi][ks] = *(const short8*)(w2bt + (size_t)(o0 + mi * 16 + col) * 128 + ks * 32 + quad * 8);
  floatx4 vzero = {0.f, 0.f, 0.f, 0.f};
  floatx4 acc[2][4];
#pragma unroll
  for (int mi = 0; mi < 2; ++mi)
#pragma unroll
    for (int ni = 0; ni < 4; ++ni) acc[mi][ni] = vzero;
  __syncthreads();
#pragma unroll
  for (int ks = 0; ks < 4; ++ks) {
    short8 bfr[4];
#pragma unroll
    for (int ni = 0; ni < 4; ++ni) {
      int row = ni * 16 + col;
      bfr[ni] = *(const short8*)&yts[row * 128 + (((ks * 4 + quad) ^ (row & 7)) * 8)];
    }
#pragma unroll
    for (int mi = 0; mi < 2; ++mi)
#pragma unroll
      for (int ni = 0; ni < 4; ++ni)
        acc[mi][ni] = __builtin_amdgcn_mfma_f32_16x16x32_bf16(afr[mi][ks], bfr[ni], acc[mi][ni], 0, 0, 0);
  }
  float s[4], q[4];
#pragma unroll
  for (int ni = 0; ni < 4; ++ni) {
    float ss = 0.f, qq = 0.f;
#pragma unroll
    for (int mi = 0; mi < 2; ++mi)
#pragma unroll
      for (int r = 0; r < 4; ++r) {
        float v = acc[mi][ni][r];
        ss += v; qq += v * v;
      }
    ss += __shfl_xor(ss, 16, 64); ss += __shfl_xor(ss, 32, 64);
    qq += __shfl_xor(qq, 16, 64); qq += __shfl_xor(qq, 32, 64);
    s[ni] = ss; q[ni] = qq;
  }
  if (quad == 0) {
#pragma unroll
    for (int ni = 0; ni < 4; ++ni) {
      red_s[wv][ni * 16 + col] = s[ni];
      red_q[wv][ni * 16 + col] = q[ni];
    }
  }
  __syncthreads();
  float mu[4], rstd[4];
#pragma unroll
  for (int ni = 0; ni < 4; ++ni) {
    int li = ni * 16 + col;
    float ts = red_s[0][li] + red_s[1][li] + red_s[2][li] + red_s[3][li];
    float tq = red_q[0][li] + red_q[1][li] + red_q[2][li] + red_q[3][li];
    float m = ts * (1.f / 128.f);
    float var = tq * (1.f / 128.f) - m * m;
    mu[ni] = m;
    rstd[ni] = rsqrtf(var + 1e-5f);
  }
  float* ob = out + (size_t)b * 128 * L_N;
#pragma unroll
  for (int mi = 0; mi < 2; ++mi)
#pragma unroll
    for (int r = 0; r < 4; ++r) {
      int o = o0 + mi * 16 + quad * 4 + r;
      float g = gs[o], bb = bs[o];
#pragma unroll
      for (int ni = 0; ni < 4; ++ni)
        ob[(size_t)o * L_N + l0 + ni * 16 + col] = (acc[mi][ni][r] - mu[ni]) * rstd[ni] * g + bb;
    }
}

// ---------------------------------------------------------------------------
extern "C" void kernel_launch(void* const* d_in, const int* in_sizes, int n_in,
                              void* d_out, int out_size, void* d_ws, size_t ws_size,
                              hipStream_t stream) {
  const float* x    = (const float*)d_in[0];
  const float* w1   = (const float*)d_in[1];
  const float* cw   = (const float*)d_in[2];
  const float* cb   = (const float*)d_in[3];
  const float* xpw  = (const float*)d_in[4];
  const float* dtw  = (const float*)d_in[5];
  const float* dtb  = (const float*)d_in[6];
  const float* alog = (const float*)d_in[7];
  const float* dpar = (const float*)d_in[8];
  const float* w2   = (const float*)d_in[9];
  const float* gam  = (const float*)d_in[10];
  const float* bet  = (const float*)d_in[11];
  float* out = (float*)d_out;

  float* ws = (float*)d_ws;
  const size_t NBL = (size_t)B_N * 128 * L_N;       // 18,874,368
  float* xdbl4 = ws;                                 // fp32 (B,4,L)  B,B,C,C
  unsigned short* dth = (unsigned short*)(ws + (size_t)B_N * 4 * L_N);  // fp16 (B,128,L)
  __hip_bfloat16* xinb = (__hip_bfloat16*)(dth + NBL);
  __hip_bfloat16* zb   = xinb + NBL;                 // bf16 (B,D,L)
  __hip_bfloat16* yb   = zb + NBL;                   // bf16 (B,D,L)
  __hip_bfloat16* w1bt = yb + NBL;
  __hip_bfloat16* w2bt = w1bt + 256 * 128;

  k_prep<<<128, 256, 0, stream>>>(w1, w2, w1bt, w2bt);
  k_inproj_conv<<<B_N * LT64, 512, 0, stream>>>(x, w1bt, cw, cb, xpw, dtw, dtb,
                                                xinb, zb, xdbl4, dth);
  k_scan<<<B_N * 128, 256, 0, stream>>>(xdbl4, dth, alog, dpar, xinb, zb, yb);
  k_outln<<<B_N * LT64, 256, 0, stream>>>(yb, w2bt, gam, bet, out);
}

// Round 11
// 291.531 us; speedup vs baseline: 1.2416x; 1.2416x over previous
//
#include <hip/hip_runtime.h>
#include <hip/hip_bf16.h>

#define B_N 16
#define L_N 9216
#define LT64 144    // L_N / 64

typedef __attribute__((ext_vector_type(8))) short short8;
typedef __attribute__((ext_vector_type(4))) float floatx4;

__device__ __forceinline__ float bfu(unsigned short u) {
  return __uint_as_float(((unsigned int)u) << 16);
}
__device__ __forceinline__ unsigned short fbf(float f) {
  __hip_bfloat16 h = __float2bfloat16(f);
  return *(unsigned short*)&h;
}

// ---------------------------------------------------------------------------
// K0: weights fp32 -> bf16
// ---------------------------------------------------------------------------
__global__ __launch_bounds__(256) void k_prep(const float* __restrict__ w1,
                                              const float* __restrict__ w2,
                                              __hip_bfloat16* __restrict__ w1bt,
                                              __hip_bfloat16* __restrict__ w2bt) {
  int i = blockIdx.x * 256 + threadIdx.x;
  if (i < 256 * 128) w1bt[i] = __float2bfloat16(w1[i]);
  if (i < 128 * 128) w2bt[i] = __float2bfloat16(w2[i]);
}

// ---------------------------------------------------------------------------
// K1: in_proj MFMA (M=256e x N=80l x K=128c), 8 waves x 2mi x 5ni.
// R5-exact structure (measured 99.4us): one-phase epilogue (acc dies there ->
// VGPR 40, no spill), fp32 cvs, plain red[8][12][64] reduce.  PROVEN LESSONS:
// do NOT two-phase the conv (acc stays live -> spill); do NOT raise
// launch_bounds arg2 past 4 (VGPR clamp -> spill); do NOT use LDS atomicAdd
// for red (8-way contention serializes); do NOT fuse dt_proj here (wash).
// ---------------------------------------------------------------------------
__global__ __launch_bounds__(512, 4) void k_inproj_conv(
    const float* __restrict__ x, const __hip_bfloat16* __restrict__ w1bt,
    const float* __restrict__ cw, const float* __restrict__ cb,
    const float* __restrict__ xpw,
    __hip_bfloat16* __restrict__ xinb, __hip_bfloat16* __restrict__ zb,
    float* __restrict__ xdblT) {
  __shared__ __align__(16) char smem1[16384];   // xs swizzled [64 l][128 c] bf16
  __shared__ __align__(16) char smem2[34816];   // xe[16][128] -> cvs[128][68] -> red[8][12][64]
  unsigned short* xs = (unsigned short*)smem1;
  unsigned short* xe = (unsigned short*)smem2;  // swizzled [16 l][128 c], l=l0-16..l0-1
  float (*cvs)[68] = (float(*)[68])smem2;
  float (*red)[12][64] = (float(*)[12][64])smem2;

  int blk = blockIdx.x, b = blk / LT64, lt = blk % LT64, l0 = lt * 64;
  int t = threadIdx.x;
  int lane = t & 63, wv = t >> 6;
  int col = lane & 15, quad = lane >> 4;

  // ---- stage x fp32 -> bf16 scattered into swizzled xe (16 l) + xs (64 l) ----
  const float* xb = x + (size_t)b * 128 * L_N + l0 - 16;
#pragma unroll
  for (int i = 0; i < 5; ++i) {
    int idx = t + i * 512;                     // 0..2559: 128 c x 20 q
    int c = idx & 127, q = idx >> 7;
    float4 v = {0.f, 0.f, 0.f, 0.f};
    if (!(lt == 0 && q < 4)) v = *(const float4*)(xb + (size_t)c * L_N + q * 4);
    int ch = c >> 3, ce = c & 7;
    if (q < 4) {
#pragma unroll
      for (int j = 0; j < 4; ++j) {
        int l = q * 4 + j;                     // 0..15
        xe[l * 128 + (((ch ^ (l & 7)) << 3) | ce)] = fbf(((const float*)&v)[j]);
      }
    } else {
#pragma unroll
      for (int j = 0; j < 4; ++j) {
        int l = q * 4 - 16 + j;                // 0..63
        xs[l * 128 + (((ch ^ (l & 7)) << 3) | ce)] = fbf(((const float*)&v)[j]);
      }
    }
  }

  int e0 = wv * 32;
  const __hip_bfloat16* wbp = w1bt + (size_t)(e0 + col) * 128 + quad * 8;
  floatx4 vzero = {0.f, 0.f, 0.f, 0.f};
  floatx4 acc[2][5];
#pragma unroll
  for (int mi = 0; mi < 2; ++mi)
#pragma unroll
    for (int ni = 0; ni < 5; ++ni) acc[mi][ni] = vzero;
  short8 a0 = *(const short8*)(wbp);
  short8 a1 = *(const short8*)(wbp + 16 * 128);
  __syncthreads();                             // B1: xe + xs ready

#pragma unroll
  for (int ks = 0; ks < 4; ++ks) {
    short8 n0, n1;
    if (ks < 3) {
      n0 = *(const short8*)(wbp + (ks + 1) * 32);
      n1 = *(const short8*)(wbp + 16 * 128 + (ks + 1) * 32);
    }
    short8 bfr[5];
    bfr[0] = *(const short8*)&xe[col * 128 + (((ks * 4 + quad) ^ (col & 7)) << 3)];
#pragma unroll
    for (int ni = 1; ni < 5; ++ni) {
      int row = (ni - 1) * 16 + col;
      bfr[ni] = *(const short8*)&xs[row * 128 + (((ks * 4 + quad) ^ (row & 7)) << 3)];
    }
#pragma unroll
    for (int ni = 0; ni < 5; ++ni) {
      acc[0][ni] = __builtin_amdgcn_mfma_f32_16x16x32_bf16(a0, bfr[ni], acc[0][ni], 0, 0, 0);
      acc[1][ni] = __builtin_amdgcn_mfma_f32_16x16x32_bf16(a1, bfr[ni], acc[1][ni], 0, 0, 0);
    }
    a0 = n0; a1 = n1;
  }
  __syncthreads();                             // B1b: LDS reads done; xe dead

  // epilogue (ONE phase): waves 0-3 -> cvs d=0..127; waves 4-7 -> z global
  if (wv >= 4) {
    __hip_bfloat16* zbase = zb + ((size_t)b * 128 + (e0 - 128)) * L_N + l0;
#pragma unroll
    for (int mi = 0; mi < 2; ++mi)
#pragma unroll
      for (int r = 0; r < 4; ++r) {
        int dr = mi * 16 + quad * 4 + r;       // within this wave's 32-row strip
#pragma unroll
        for (int ni = 1; ni < 5; ++ni)
          zbase[(size_t)dr * L_N + (ni - 1) * 16 + col] = __float2bfloat16(acc[mi][ni][r]);
      }
  } else {
#pragma unroll
    for (int mi = 0; mi < 2; ++mi)
#pragma unroll
      for (int r = 0; r < 4; ++r) {
        int d = e0 + mi * 16 + quad * 4 + r;   // 0..127
        if (col >= 13) cvs[d][col - 13] = acc[mi][0][r];
#pragma unroll
        for (int ni = 1; ni < 5; ++ni) cvs[d][3 + (ni - 1) * 16 + col] = acc[mi][ni][r];
      }
  }
  __syncthreads();                             // B2: cvs ready

  // conv + SiLU + x_proj partials; wave wv owns d in [wv*16, wv*16+16)
  float part[12];
#pragma unroll
  for (int m = 0; m < 12; ++m) part[m] = 0.f;
  for (int dd = 0; dd < 16; ++dd) {
    int d = wv * 16 + dd;
    float v = cb[d] + cw[d * 4 + 0] * cvs[d][lane] + cw[d * 4 + 1] * cvs[d][lane + 1]
                    + cw[d * 4 + 2] * cvs[d][lane + 2] + cw[d * 4 + 3] * cvs[d][lane + 3];
    v = v / (1.f + __expf(-v));                // SiLU
    xinb[((size_t)b * 128 + d) * L_N + l0 + lane] = __float2bfloat16(v);
#pragma unroll
    for (int m = 0; m < 12; ++m) part[m] += xpw[m * 128 + d] * v;
  }
  __syncthreads();                             // B3: cvs dead -> red aliases
#pragma unroll
  for (int m = 0; m < 12; ++m) red[wv][m][lane] = part[m];
  __syncthreads();                             // B4
  for (int idx = t; idx < 12 * 64; idx += 512) {
    int m = idx >> 6, l = idx & 63;
    float s = 0.f;
#pragma unroll
    for (int w8 = 0; w8 < 8; ++w8) s += red[w8][m][l];
    xdblT[((size_t)b * 12 + m) * L_N + l0 + l] = s;
  }
}

// ---------------------------------------------------------------------------
// K3: dt_proj + softplus + scan (D_STATE=2) + y + z-gate.
// Block per (b,d); 9 tiles of 1024 l.  Single barrier per tile: agg + carry
// double-buffered on tile parity (carry[p^1] written post-barrier, read after
// the NEXT barrier -> ordered).
// ---------------------------------------------------------------------------
__global__ __launch_bounds__(256) void k_scan(
    const float* __restrict__ xdblT, const float* __restrict__ dtw,
    const float* __restrict__ dtb, const float* __restrict__ alog,
    const float* __restrict__ dpar,
    const __hip_bfloat16* __restrict__ xinb, const __hip_bfloat16* __restrict__ zb,
    __hip_bfloat16* __restrict__ yb) {
  __shared__ float agg[2][4][4];
  __shared__ float carry[2][2];
  int blk = blockIdx.x, b = blk >> 7, d = blk & 127;
  int t = threadIdx.x, lane = t & 63, wv = t >> 6;
  float A0 = -__expf(alog[2 * d]), A1 = -__expf(alog[2 * d + 1]);
  float Dv = dpar[d], dtbv = dtb[d];
  float w[8];
#pragma unroll
  for (int i = 0; i < 8; ++i) w[i] = dtw[d * 8 + i];
  if (t == 0) { carry[0][0] = 0.f; carry[0][1] = 0.f; }
  __syncthreads();
  const float* xdT = xdblT + (size_t)b * 12 * L_N;
  const unsigned short* xi = (const unsigned short*)xinb + ((size_t)b * 128 + d) * L_N;
  const unsigned short* zr = (const unsigned short*)zb + ((size_t)b * 128 + d) * L_N;
  unsigned short* yo = (unsigned short*)yb + ((size_t)b * 128 + d) * L_N;
  for (int it = 0; it < 9; ++it) {
    int p = it & 1;
    int lb = it * 1024 + t * 4;
    float4 q[12];
#pragma unroll
    for (int m = 0; m < 12; ++m) q[m] = *(const float4*)(xdT + (size_t)m * L_N + lb);
    ushort4 xu = *(const ushort4*)(xi + lb);
    ushort4 zu = *(const ushort4*)(zr + lb);
    float xv[4] = {bfu(xu.x), bfu(xu.y), bfu(xu.z), bfu(xu.w)};
    float zv[4] = {bfu(zu.x), bfu(zu.y), bfu(zu.z), bfu(zu.w)};
    float A0p[4], X0p[4], A1p[4], X1p[4];
#pragma unroll
    for (int j = 0; j < 4; ++j) {
      float dtp = dtbv;
#pragma unroll
      for (int m = 0; m < 8; ++m) dtp += w[m] * ((const float*)&q[m])[j];
      float dt = (dtp > 15.f) ? dtp : __logf(1.f + __expf(dtp));  // softplus
      float a0 = __expf(dt * A0), a1 = __expf(dt * A1);
      float dtx = dt * xv[j];
      float x0 = dtx * ((const float*)&q[8])[j];
      float x1 = dtx * ((const float*)&q[9])[j];
      if (j == 0) { A0p[0] = a0; X0p[0] = x0; A1p[0] = a1; X1p[0] = x1; }
      else {
        A0p[j] = a0 * A0p[j - 1]; X0p[j] = a0 * X0p[j - 1] + x0;
        A1p[j] = a1 * A1p[j - 1]; X1p[j] = a1 * X1p[j - 1] + x1;
      }
    }
    float wA0 = A0p[3], wX0 = X0p[3], wA1 = A1p[3], wX1 = X1p[3];
#pragma unroll
    for (int off = 1; off < 64; off <<= 1) {
      float pA0 = __shfl_up(wA0, off, 64), pX0 = __shfl_up(wX0, off, 64);
      float pA1 = __shfl_up(wA1, off, 64), pX1 = __shfl_up(wX1, off, 64);
      if (lane >= off) {
        wX0 += wA0 * pX0; wA0 *= pA0;
        wX1 += wA1 * pX1; wA1 *= pA1;
      }
    }
    if (lane == 63) { agg[p][wv][0] = wA0; agg[p][wv][1] = wX0; agg[p][wv][2] = wA1; agg[p][wv][3] = wX1; }
    float eA0 = __shfl_up(wA0, 1, 64), eX0 = __shfl_up(wX0, 1, 64);
    float eA1 = __shfl_up(wA1, 1, 64), eX1 = __shfl_up(wX1, 1, 64);
    if (lane == 0) { eA0 = 1.f; eX0 = 0.f; eA1 = 1.f; eX1 = 0.f; }
    __syncthreads();                           // agg[p] + carry[p] ready
    float h0 = carry[p][0], h1 = carry[p][1];
    for (int jw = 0; jw < wv; ++jw) {          // wave-uniform
      h0 = agg[p][jw][0] * h0 + agg[p][jw][1];
      h1 = agg[p][jw][2] * h1 + agg[p][jw][3];
    }
    h0 = eA0 * h0 + eX0;                       // lane input state
    h1 = eA1 * h1 + eX1;
    if (t == 255) {                            // other parity buffer: no race
      carry[p ^ 1][0] = A0p[3] * h0 + X0p[3];
      carry[p ^ 1][1] = A1p[3] * h1 + X1p[3];
    }
    ushort4 yu;
    unsigned short* yp = (unsigned short*)&yu;
#pragma unroll
    for (int j = 0; j < 4; ++j) {
      float hh0 = A0p[j] * h0 + X0p[j];
      float hh1 = A1p[j] * h1 + X1p[j];
      float y = hh0 * ((const float*)&q[10])[j] + hh1 * ((const float*)&q[11])[j] + Dv * xv[j];
      y *= zv[j] / (1.f + __expf(-zv[j]));
      yp[j] = fbf(y);
    }
    *(ushort4*)(yo + lb) = yu;
  }
}

// ---------------------------------------------------------------------------
// K4: out_proj MFMA (M=128o x N=64l x K=128d) + LayerNorm + NCHW write.
// NEW: yb scattered bf16-scalar DIRECTLY into the swizzled MFMA B-tile
// during the global load (no st[][] stage, no gather phase, one less
// barrier).  LDS 19.5KB -> 8 blocks/CU (was 36.5KB -> 4).
// ---------------------------------------------------------------------------
__global__ __launch_bounds__(256) void k_outln(
    const __hip_bfloat16* __restrict__ yb, const __hip_bfloat16* __restrict__ w2bt,
    const float* __restrict__ gam, const float* __restrict__ bet,
    float* __restrict__ out) {
  __shared__ unsigned short yts[64 * 128];      // swizzled [64 l][128 d]
  __shared__ float red_s[4][64], red_q[4][64];
  __shared__ float gs[128], bs[128];
  int blk = blockIdx.x, b = blk / LT64, lt = blk % LT64, l0 = lt * 64;
  int t = threadIdx.x;
  if (t < 128) { gs[t] = gam[t]; bs[t] = bet[t]; }
  const unsigned short* ybb = (const unsigned short*)yb + (size_t)b * 128 * L_N + l0;
#pragma unroll
  for (int i = 0; i < 8; ++i) {
    int idx = t + i * 256;              // 2048 tasks: 128 d x 16 l-quads
    int dd = idx >> 4, l4 = (idx & 15) * 4;
    ushort4 v = *(const ushort4*)(ybb + (size_t)dd * L_N + l4);
    int ch = dd >> 3, ce = dd & 7;
    yts[(l4 + 0) * 128 + (((ch ^ ((l4 + 0) & 7)) << 3) | ce)] = v.x;
    yts[(l4 + 1) * 128 + (((ch ^ ((l4 + 1) & 7)) << 3) | ce)] = v.y;
    yts[(l4 + 2) * 128 + (((ch ^ ((l4 + 2) & 7)) << 3) | ce)] = v.z;
    yts[(l4 + 3) * 128 + (((ch ^ ((l4 + 3) & 7)) << 3) | ce)] = v.w;
  }
  int lane = t & 63, wv = t >> 6;
  int col = lane & 15, quad = lane >> 4;
  int o0 = wv * 32;
  short8 afr[2][4];
#pragma unroll
  for (int mi = 0; mi < 2; ++mi)
#pragma unroll
    for (int ks = 0; ks < 4; ++ks)
      afr[mi][ks] = *(const short8*)(w2bt + (size_t)(o0 + mi * 16 + col) * 128 + ks * 32 + quad * 8);
  floatx4 vzero = {0.f, 0.f, 0.f, 0.f};
  floatx4 acc[2][4];
#pragma unroll
  for (int mi = 0; mi < 2; ++mi)
#pragma unroll
    for (int ni = 0; ni < 4; ++ni) acc[mi][ni] = vzero;
  __syncthreads();                     // yts ready
#pragma unroll
  for (int ks = 0; ks < 4; ++ks) {
    short8 bfr[4];
#pragma unroll
    for (int ni = 0; ni < 4; ++ni) {
      int row = ni * 16 + col;
      bfr[ni] = *(const short8*)&yts[row * 128 + (((ks * 4 + quad) ^ (row & 7)) << 3)];
    }
#pragma unroll
    for (int mi = 0; mi < 2; ++mi)
#pragma unroll
      for (int ni = 0; ni < 4; ++ni)
        acc[mi][ni] = __builtin_amdgcn_mfma_f32_16x16x32_bf16(afr[mi][ks], bfr[ni], acc[mi][ni], 0, 0, 0);
  }
  float s[4], q[4];
#pragma unroll
  for (int ni = 0; ni < 4; ++ni) {
    float ss = 0.f, qq = 0.f;
#pragma unroll
    for (int mi = 0; mi < 2; ++mi)
#pragma unroll
      for (int r = 0; r < 4; ++r) {
        float v = acc[mi][ni][r];
        ss += v; qq += v * v;
      }
    ss += __shfl_xor(ss, 16, 64); ss += __shfl_xor(ss, 32, 64);
    qq += __shfl_xor(qq, 16, 64); qq += __shfl_xor(qq, 32, 64);
    s[ni] = ss; q[ni] = qq;
  }
  if (quad == 0) {
#pragma unroll
    for (int ni = 0; ni < 4; ++ni) {
      red_s[wv][ni * 16 + col] = s[ni];
      red_q[wv][ni * 16 + col] = q[ni];
    }
  }
  __syncthreads();
  float mu[4], rstd[4];
#pragma unroll
  for (int ni = 0; ni < 4; ++ni) {
    int li = ni * 16 + col;
    float ts = red_s[0][li] + red_s[1][li] + red_s[2][li] + red_s[3][li];
    float tq = red_q[0][li] + red_q[1][li] + red_q[2][li] + red_q[3][li];
    float m = ts * (1.f / 128.f);
    float var = tq * (1.f / 128.f) - m * m;
    mu[ni] = m;
    rstd[ni] = rsqrtf(var + 1e-5f);
  }
  float* ob = out + (size_t)b * 128 * L_N;
#pragma unroll
  for (int mi = 0; mi < 2; ++mi)
#pragma unroll
    for (int r = 0; r < 4; ++r) {
      int o = o0 + mi * 16 + quad * 4 + r;
      float g = gs[o], bb = bs[o];
#pragma unroll
      for (int ni = 0; ni < 4; ++ni)
        ob[(size_t)o * L_N + l0 + ni * 16 + col] = (acc[mi][ni][r] - mu[ni]) * rstd[ni] * g + bb;
    }
}

// ---------------------------------------------------------------------------
extern "C" void kernel_launch(void* const* d_in, const int* in_sizes, int n_in,
                              void* d_out, int out_size, void* d_ws, size_t ws_size,
                              hipStream_t stream) {
  const float* x    = (const float*)d_in[0];
  const float* w1   = (const float*)d_in[1];
  const float* cw   = (const float*)d_in[2];
  const float* cb   = (const float*)d_in[3];
  const float* xpw  = (const float*)d_in[4];
  const float* dtw  = (const float*)d_in[5];
  const float* dtb  = (const float*)d_in[6];
  const float* alog = (const float*)d_in[7];
  const float* dpar = (const float*)d_in[8];
  const float* w2   = (const float*)d_in[9];
  const float* gam  = (const float*)d_in[10];
  const float* bet  = (const float*)d_in[11];
  float* out = (float*)d_out;

  float* ws = (float*)d_ws;
  const size_t NBL = (size_t)B_N * 128 * L_N;      // 18,874,368
  float* xdblT = ws;                                // fp32 (B,12,L)
  __hip_bfloat16* xinb = (__hip_bfloat16*)(ws + (size_t)B_N * 12 * L_N);
  __hip_bfloat16* zb   = xinb + NBL;                // bf16 (B,D,L)
  __hip_bfloat16* yb   = zb + NBL;                  // bf16 (B,D,L)
  __hip_bfloat16* w1bt = yb + NBL;
  __hip_bfloat16* w2bt = w1bt + 256 * 128;

  k_prep<<<128, 256, 0, stream>>>(w1, w2, w1bt, w2bt);
  k_inproj_conv<<<B_N * LT64, 512, 0, stream>>>(x, w1bt, cw, cb, xpw, xinb, zb, xdblT);
  k_scan<<<B_N * 128, 256, 0, stream>>>(xdblT, dtw, dtb, alog, dpar, xinb, zb, yb);
  k_outln<<<B_N * LT64, 256, 0, stream>>>(yb, w2bt, gam, bet, out);
}